// Round 16
// baseline (2378.471 us; speedup 1.0000x reference)
//
#include <hip/hip_runtime.h>

// ---------------------------------------------------------------------------
// ROUND 28: GEMM tile widened to BM=256 x BN=128, 8 waves (512 threads),
// 4(M)x2(N) wave quadrants. PIPE3 loop unchanged in form: BK=32 triple
// buffer (72KB -> 2 blocks/CU, 16 waves/CU), counted vmcnt(3) (3 loads/wave/
// tile now), ONEBAR schedule (r25/r26 best). FLOP per staged LDS byte x1.33.
// Same chunk swizzle (16-row x 32-col chunks), same swap epilogues (bf16 epi
// [256][128]=64KB fits buffer; read phase TPB-parametric). Head GEMM on the
// legacy 256-thread path via TPB template param. attn/LN/embed unchanged.
// fp32 residual/output. B=128 T=256 E=384 H=6 HS=64 L=6 V=78 FF=1536.
// ---------------------------------------------------------------------------

#define Bc 128
#define Tc 256
#define Ec 384
#define Hc 6
#define HSc 64
#define Lc 6
#define Vc 78
#define FFc 1536
#define Mc (Bc * Tc)  // 32768 tokens

typedef unsigned short u16;
using bf16x8 = __attribute__((ext_vector_type(8))) short;
using f32x4 = __attribute__((ext_vector_type(4))) float;

__device__ __forceinline__ float b2f(u16 u) {
    union { float f; unsigned int i; } x;
    x.i = ((unsigned int)u) << 16;
    return x.f;
}
__device__ __forceinline__ u16 f2b(float f) {
    union { float f; unsigned int u; } x;
    x.f = f;
    unsigned int r = x.u + 0x7fffu + ((x.u >> 16) & 1u);  // RNE
    return (u16)(r >> 16);
}

// async global->LDS, 16B per lane; dest is wave-uniform base + lane*16
__device__ __forceinline__ void gload_lds16(const u16* g, u16* l) {
    __builtin_amdgcn_global_load_lds(
        (const __attribute__((address_space(1))) unsigned int*)g,
        (__attribute__((address_space(3))) unsigned int*)l, 16, 0, 0);
}

__global__ __launch_bounds__(256) void poison_kernel(
    float* __restrict__ out, int n, float val) {
    int i = blockIdx.x * 256 + threadIdx.x;
    if (i < n) out[i] = val;
}

// --- weight pre-transpose to bf16 [N][K] ------------------------------------
__global__ __launch_bounds__(256) void trans_qkv_kernel(
    const float* __restrict__ in, u16* __restrict__ out) {
    int i = blockIdx.x * 256 + threadIdx.x;  // < L*H*E*192
    if (i >= Lc * Hc * Ec * 192) return;
    int f = i % 192;
    int r = i / 192;
    int e = r % Ec; r /= Ec;
    int h = r % Hc;
    int l = r / Hc;
    out[((size_t)l * 1152 + h * 192 + f) * Ec + e] = f2b(in[i]);
}
__global__ __launch_bounds__(256) void trans_w_kernel(
    const float* __restrict__ in, u16* __restrict__ out, int K, int N) {
    int i = blockIdx.x * 256 + threadIdx.x;  // < L*K*N
    if (i >= Lc * K * N) return;
    int n = i % N;
    int r = i / N;
    int k = r % K;
    int l = r / K;
    out[((size_t)l * N + n) * K + k] = f2b(in[i]);
}
// head: in[e*Vc+v] -> out[v*Ec+e], v<Vc (rows Vc..127 pre-zeroed)
__global__ __launch_bounds__(256) void trans_head_kernel(
    const float* __restrict__ in, u16* __restrict__ out) {
    int i = blockIdx.x * 256 + threadIdx.x;  // < Ec*Vc
    if (i >= Ec * Vc) return;
    int v = i % Vc, e = i / Vc;
    out[(size_t)v * Ec + e] = f2b(in[i]);
}

// --- x[bt,e4] = tok_emb[ctx[bt],e4] + pos_emb[t,e4]  (fp32, f32x4) ----------
__global__ __launch_bounds__(256) void embed_kernel(
    const int* __restrict__ ctx, const float* __restrict__ tok,
    const float* __restrict__ pos, float* __restrict__ x) {
    int i = blockIdx.x * 256 + threadIdx.x;  // over Mc*96
    if (i >= Mc * 96) return;
    int c4 = (i % 96) * 4, bt = i / 96, t = bt % Tc;
    f32x4 tv = *reinterpret_cast<const f32x4*>(&tok[ctx[bt] * Ec + c4]);
    f32x4 pv = *reinterpret_cast<const f32x4*>(&pos[t * Ec + c4]);
    *reinterpret_cast<f32x4*>(&x[(size_t)bt * Ec + c4]) = tv + pv;
}

// --- layernorm fp32 in -> bf16 out: one wave per row (float2/ushort2) -------
__global__ __launch_bounds__(256) void ln_kernel(
    const float* __restrict__ X, u16* __restrict__ Y,
    const float* __restrict__ g, const float* __restrict__ b, int nrows) {
    int row = blockIdx.x * 4 + (threadIdx.x >> 6);
    int lane = threadIdx.x & 63;
    if (row >= nrows) return;
    const float* xr = X + (size_t)row * Ec;
    float2 v[3];
    float s = 0.f;
#pragma unroll
    for (int i = 0; i < 3; ++i) {
        v[i] = *reinterpret_cast<const float2*>(&xr[2 * lane + 128 * i]);
        s += v[i].x + v[i].y;
    }
#pragma unroll
    for (int off = 32; off >= 1; off >>= 1) s += __shfl_xor(s, off, 64);
    float mean = s * (1.0f / Ec);
    float s2 = 0.f;
#pragma unroll
    for (int i = 0; i < 3; ++i) {
        float dx = v[i].x - mean, dy = v[i].y - mean;
        s2 += dx * dx + dy * dy;
    }
#pragma unroll
    for (int off = 32; off >= 1; off >>= 1) s2 += __shfl_xor(s2, off, 64);
    float rstd = rsqrtf(s2 * (1.0f / Ec) + 1e-5f);
    u16* yr = Y + (size_t)row * Ec;
#pragma unroll
    for (int i = 0; i < 3; ++i) {
        int e = 2 * lane + 128 * i;
        float2 gv = *reinterpret_cast<const float2*>(&g[e]);
        float2 bv = *reinterpret_cast<const float2*>(&b[e]);
        ushort2 ov;
        ov.x = f2b((v[i].x - mean) * rstd * gv.x + bv.x);
        ov.y = f2b((v[i].y - mean) * rstd * gv.y + bv.y);
        *reinterpret_cast<ushort2*>(&yr[e]) = ov;
    }
}

// --- MFMA GEMM: C[*, ldC] = A[M,K](bf16) @ Wt[N,K]^T(bf16) [+bias][+R] ------
// PIPE3=true (TPB=512): BM=256 x BN=128, 8 waves (4Mx2N of 64x64 each).
//   BK=32 triple buffer (72KB), per-wave 3 chunks/tile (A:16, B:8 chunks of
//   16rows x 32cols), counted vmcnt(3), ONEBAR schedule: vmcnt;bar;
//   stage(t+2); compute(t). Chunk swizzle as r21: lane l -> row 16c+(l>>2),
//   slot l&3, src col slot (l&3)^((l>>3)&3); read csw = quad^((r16>>1)&3).
//   K%32==0, K/32>=3.
// PIPE3=false (TPB=256): r13 legacy loop, BM=128 (head GEMM).
// SWAP = VECEPI: operand-swapped mfma -> acc[mi][ni] = 4 consecutive n
//   (base n0+wn+ni*16+quad*4) of row m0+wm+mi*16+r16 (r18-verified layout).
// Epilogues (NV % 128 == 0 required for VECEPI):
//   VECEPI && OUTBF16 : f32x4 bias -> ushort4 swizzled LDS writes ->
//                       b128 coalesced global stores ([BM][128] stage).
//   VECEPI && !OUTBF16: direct f32x4 bias/R/store, no LDS.
//   !VECEPI           : scalar epilogue with NV guard (head GEMM).
template <bool RELU, bool RESID, bool OUTBF16, bool VECEPI, bool PIPE3,
          int TPB>
__global__ __launch_bounds__(TPB) void mfma_gemm(
    const u16* __restrict__ A, const u16* __restrict__ Wt,
    const float* __restrict__ bias, const float* R, void* C,
    int K, int ldC, int NV) {
    constexpr bool SWAP = VECEPI;
    constexpr int BM = PIPE3 ? 256 : 128;
    __shared__ __align__(16) u16 smem[PIPE3 ? 36864 : 16384];
    int tid = threadIdx.x;

    // bijective XCD swizzle (m204): contiguous bid chunk per XCD
    int nwg = gridDim.x * gridDim.y;
    int bid = blockIdx.y * gridDim.x + blockIdx.x;
    int q = nwg >> 3, r = nwg & 7;
    int xcd = bid & 7, idx = bid >> 3;
    int swz = (xcd < r ? xcd * (q + 1) : r * (q + 1) + (xcd - r) * q) + idx;
    int bx = swz % gridDim.x, by = swz / gridDim.x;
    int m0 = by * BM, n0 = bx * 128;

    int w = tid >> 6, lane = tid & 63;
    // PIPE3: 8 waves, 4Mx2N; legacy: 4 waves, 2Mx2N
    int wm = PIPE3 ? (w >> 1) * 64 : (w >> 1) * 64;
    int wn = (w & 1) * 64;
    int r16 = lane & 15, quad = lane >> 4;

    f32x4 acc[4][4] = {};

    if constexpr (PIPE3) {
        // LDS layout: As3 bufs at 0 (stride 256*32=8192/buf, 3 bufs),
        //             Bs3 bufs at 24576 (stride 128*32=4096/buf, 3 bufs).
        int colsw = ((lane & 3) ^ ((lane >> 3) & 3)) * 8;
        const u16* p[3];
        u16* dst0[3];
        int bstride[3];
#pragma unroll
        for (int j = 0; j < 3; ++j) {
            int c = 3 * w + j;  // 0..23: A chunks 0..15, B chunks 16..23
            if (c < 16) {
                p[j] = A + (size_t)(m0 + 16 * c + (lane >> 2)) * K + colsw;
                dst0[j] = smem + 16 * c * 32;
                bstride[j] = 256 * 32;
            } else {
                int cb = c - 16;
                p[j] = Wt + (size_t)(n0 + 16 * cb + (lane >> 2)) * K + colsw;
                dst0[j] = smem + 3 * 256 * 32 + 16 * cb * 32;
                bstride[j] = 128 * 32;
            }
        }

        auto stage3 = [&](int buf, int t) {
            int k0 = t * 32;
#pragma unroll
            for (int j = 0; j < 3; ++j)
                gload_lds16(p[j] + k0, dst0[j] + buf * bstride[j]);
        };
        int csw = (quad ^ ((r16 >> 1) & 3)) * 8;
        auto compute3 = [&](int buf) {
            const u16* Ab = smem + buf * (256 * 32);
            const u16* Bb = smem + 3 * 256 * 32 + buf * (128 * 32);
            bf16x8 af[4], bf[4];
#pragma unroll
            for (int i = 0; i < 4; ++i) {
                af[i] = *reinterpret_cast<const bf16x8*>(
                    &Ab[(wm + i * 16 + r16) * 32 + csw]);
                bf[i] = *reinterpret_cast<const bf16x8*>(
                    &Bb[(wn + i * 16 + r16) * 32 + csw]);
            }
#pragma unroll
            for (int mi = 0; mi < 4; ++mi)
#pragma unroll
                for (int ni = 0; ni < 4; ++ni) {
                    if (SWAP)
                        acc[mi][ni] = __builtin_amdgcn_mfma_f32_16x16x32_bf16(
                            bf[ni], af[mi], acc[mi][ni], 0, 0, 0);
                    else
                        acc[mi][ni] = __builtin_amdgcn_mfma_f32_16x16x32_bf16(
                            af[mi], bf[ni], acc[mi][ni], 0, 0, 0);
                }
        };

        int nt = K >> 5;  // >= 3 required
        stage3(0, 0);
        stage3(1, 1);
        int buf = 0;
        for (int t = 0; t < nt - 1; ++t) {
            // per-wave: tile-t loads landed (oldest 3 of 6 outstanding)
            asm volatile("s_waitcnt vmcnt(3)" ::: "memory");
            __builtin_amdgcn_s_barrier();
            __builtin_amdgcn_sched_barrier(0);
            if (t + 2 < nt) {  // stage next-next tile BEFORE compute
                int b2 = buf + 2;
                if (b2 >= 3) b2 -= 3;
                stage3(b2, t + 2);
            }
            compute3(buf);
            buf = (buf == 2) ? 0 : buf + 1;
        }
        asm volatile("s_waitcnt vmcnt(0)" ::: "memory");  // last tile landed
        __builtin_amdgcn_s_barrier();
        __builtin_amdgcn_sched_barrier(0);
        compute3(buf);
    } else {
        u16(*As)[64] = (u16(*)[64])smem;
        u16(*Bs)[64] = (u16(*)[64])(smem + 128 * 64);
        // legacy staging: wave w owns 1KB chunks {4w..4w+3} of each tile.
        int lrow = lane >> 3;
        int scol = ((lane & 7) ^ lrow) * 8;
        const u16* ap[4];
        const u16* bp[4];
#pragma unroll
        for (int j = 0; j < 4; ++j) {
            int row = (w * 4 + j) * 8 + lrow;
            ap[j] = A + (size_t)(m0 + row) * K + scol;
            bp[j] = Wt + (size_t)(n0 + row) * K + scol;
        }
        for (int k0 = 0; k0 < K; k0 += 64) {
            __syncthreads();
#pragma unroll
            for (int j = 0; j < 4; ++j) {
                gload_lds16(ap[j], &As[(w * 4 + j) * 8][0]);
                gload_lds16(bp[j], &Bs[(w * 4 + j) * 8][0]);
                ap[j] += 64;
                bp[j] += 64;
            }
            __syncthreads();
#pragma unroll
            for (int kk = 0; kk < 2; ++kk) {
                int csw = ((kk * 4 + quad) ^ (r16 & 7)) * 8;  // swizzled col
                bf16x8 af[4], bf[4];
#pragma unroll
                for (int i = 0; i < 4; ++i) {
                    af[i] = *reinterpret_cast<const bf16x8*>(
                        &As[wm + i * 16 + r16][csw]);
                    bf[i] = *reinterpret_cast<const bf16x8*>(
                        &Bs[wn + i * 16 + r16][csw]);
                }
#pragma unroll
                for (int mi = 0; mi < 4; ++mi)
#pragma unroll
                    for (int ni = 0; ni < 4; ++ni) {
                        if (SWAP)
                            acc[mi][ni] = __builtin_amdgcn_mfma_f32_16x16x32_bf16(
                                bf[ni], af[mi], acc[mi][ni], 0, 0, 0);
                        else
                            acc[mi][ni] = __builtin_amdgcn_mfma_f32_16x16x32_bf16(
                                af[mi], bf[ni], acc[mi][ni], 0, 0, 0);
                    }
            }
        }
    }

    // ---- epilogue ----------------------------------------------------------
    if (VECEPI && OUTBF16) {
        // swapped layout: acc[mi][ni] = 4 consecutive n (gn..gn+3) of row
        // m0+wm+mi*16+r16, gn = n0+wn+ni*16+quad*4.
        f32x4 bv4[4];
#pragma unroll
        for (int ni = 0; ni < 4; ++ni) {
            int gn = n0 + wn + ni * 16 + quad * 4;
            if (bias)
                bv4[ni] = *reinterpret_cast<const f32x4*>(&bias[gn]);
            else
                bv4[ni] = f32x4{0.f, 0.f, 0.f, 0.f};
        }
        __syncthreads();  // main-loop LDS reads done
        // write: [BM][128] u16, 8-elem chunk swizzled pc = cc ^ (row&15)
#pragma unroll
        for (int mi = 0; mi < 4; ++mi) {
            int row = wm + mi * 16 + r16;
#pragma unroll
            for (int ni = 0; ni < 4; ++ni) {
                int colb = wn + ni * 16 + quad * 4;
                f32x4 v = acc[mi][ni] + bv4[ni];
                if (RELU) {
#pragma unroll
                    for (int e = 0; e < 4; ++e) v[e] = fmaxf(v[e], 0.f);
                }
                ushort4 ov;
                ov.x = f2b(v[0]);
                ov.y = f2b(v[1]);
                ov.z = f2b(v[2]);
                ov.w = f2b(v[3]);
                int pc = (colb >> 3) ^ (row & 15);
                *reinterpret_cast<ushort4*>(
                    &smem[row * 128 + pc * 8 + (colb & 7)]) = ov;
            }
        }
        __syncthreads();
        // read + store: thread t -> rows (t>>3) + (TPB/8)*i, chunk (t&7)+8h
        u16* cp = (u16*)C;
        constexpr int RPI = TPB / 8;        // rows covered per iteration
        constexpr int NIT = BM / RPI;       // iterations
#pragma unroll
        for (int i = 0; i < NIT; ++i) {
            int row = (tid >> 3) + RPI * i;
#pragma unroll
            for (int h = 0; h < 2; ++h) {
                int lc = (tid & 7) + 8 * h;
                int pc = lc ^ (row & 15);
                bf16x8 val = *reinterpret_cast<const bf16x8*>(
                    &smem[row * 128 + pc * 8]);
                *reinterpret_cast<bf16x8*>(
                    &cp[(size_t)(m0 + row) * ldC + n0 + lc * 8]) = val;
            }
        }
    } else if (VECEPI) {
        // operand-swapped fp32 path: direct f32x4 bias/R/store.
        float* cp = (float*)C;
        f32x4 bv4[4];
#pragma unroll
        for (int ni = 0; ni < 4; ++ni) {
            int gn = n0 + wn + ni * 16 + quad * 4;
            if (bias)
                bv4[ni] = *reinterpret_cast<const f32x4*>(&bias[gn]);
            else
                bv4[ni] = f32x4{0.f, 0.f, 0.f, 0.f};
        }
#pragma unroll
        for (int mi = 0; mi < 4; ++mi) {
            int gm = m0 + wm + mi * 16 + r16;
#pragma unroll
            for (int ni = 0; ni < 4; ++ni) {
                int gn = n0 + wn + ni * 16 + quad * 4;
                size_t goff = (size_t)gm * ldC + gn;
                f32x4 v = acc[mi][ni] + bv4[ni];
                if (RELU) {
#pragma unroll
                    for (int e = 0; e < 4; ++e) v[e] = fmaxf(v[e], 0.f);
                }
                if (RESID) v += *reinterpret_cast<const f32x4*>(&R[goff]);
                *reinterpret_cast<f32x4*>(&cp[goff]) = v;
            }
        }
    } else {
        // scalar epilogue with NV guard (head GEMM; unswapped layout)
#pragma unroll
        for (int mi = 0; mi < 4; ++mi)
#pragma unroll
            for (int ni = 0; ni < 4; ++ni) {
                int gn = n0 + wn + ni * 16 + r16;
                if (gn >= NV) continue;
                float bvs = bias ? bias[gn] : 0.f;
#pragma unroll
                for (int reg = 0; reg < 4; ++reg) {
                    int gm = m0 + wm + mi * 16 + quad * 4 + reg;
                    float v = acc[mi][ni][reg] + bvs;
                    if (RESID) v += R[(size_t)gm * ldC + gn];
                    if (RELU) v = fmaxf(v, 0.f);
                    if (OUTBF16)
                        ((u16*)C)[(size_t)gm * ldC + gn] = f2b(v);
                    else
                        ((float*)C)[(size_t)gm * ldC + gn] = v;
                }
            }
    }
}

// --- MFMA flash attention: T14 reg-prefetch + Vt XOR-swizzle (r24) ----------
// Vt store: logical col t=sr of row d lands at chunk (sr>>3)^((d>>3)&7),
// slot sr&7. Read of logical chunk q: physical q^((d>>3)&7). 8-way -> 2-way.
__global__ __launch_bounds__(256) void attn_kernel(
    const u16* __restrict__ qkv, u16* __restrict__ o) {
    __shared__ u16 Qs[64][72];
    __shared__ u16 Ks[64][72];
    __shared__ u16 Vt[64][72];
    __shared__ u16 Ps[4][16][72];
    int tid = threadIdx.x;
    int tt = blockIdx.x, h = blockIdx.y, b = blockIdx.z;
    int w = tid >> 6, lane = tid & 63;
    int r16 = lane & 15, quad = lane >> 4;
    int t0 = tt * 64;
    const u16* base = qkv + (size_t)b * Tc * 1152 + h * 192;

    int sr = tid >> 2, sd = (tid & 3) * 16;
    {
        const u16* src = base + (size_t)(t0 + sr) * 1152 + sd;
        *reinterpret_cast<uint4*>(&Qs[sr][sd]) =
            *reinterpret_cast<const uint4*>(src);
        *reinterpret_cast<uint4*>(&Qs[sr][sd + 8]) =
            *reinterpret_cast<const uint4*>(src + 8);
    }
    __syncthreads();
    // hoisted Q fragments (loop-invariant; compiler can't hoist across barriers)
    bf16x8 aq0 = *reinterpret_cast<const bf16x8*>(&Qs[w * 16 + r16][quad * 8]);
    bf16x8 aq1 = *reinterpret_cast<const bf16x8*>(&Qs[w * 16 + r16][32 + quad * 8]);

    // prefetch tile 0 K/V into registers
    uint4 kr0, kr1, vr0, vr1;
    {
        const u16* ks = base + (size_t)sr * 1152 + 64 + sd;
        kr0 = *reinterpret_cast<const uint4*>(ks);
        kr1 = *reinterpret_cast<const uint4*>(ks + 8);
        const u16* vs = base + (size_t)sr * 1152 + 128 + sd;
        vr0 = *reinterpret_cast<const uint4*>(vs);
        vr1 = *reinterpret_cast<const uint4*>(vs + 8);
    }
    int vslot = sr & 7, vchk = sr >> 3;  // for swizzled Vt store

    float m_run[4], l_run[4];
#pragma unroll
    for (int r = 0; r < 4; ++r) { m_run[r] = -3.0e38f; l_run[r] = 0.f; }
    f32x4 acc_o[4] = {};

    for (int st = 0; st <= tt; ++st) {
        __syncthreads();  // prev reads of Ks/Vt done
        {
            *reinterpret_cast<uint4*>(&Ks[sr][sd]) = kr0;
            *reinterpret_cast<uint4*>(&Ks[sr][sd + 8]) = kr1;
            u16 tv[16];
            *reinterpret_cast<uint4*>(tv) = vr0;
            *reinterpret_cast<uint4*>(tv + 8) = vr1;
#pragma unroll
            for (int j = 0; j < 16; ++j) {
                int row = sd + j;
                int pc = vchk ^ ((row >> 3) & 7);
                Vt[row][pc * 8 + vslot] = tv[j];
            }
        }
        __syncthreads();  // staged tile visible
        if (st < tt) {  // issue next-tile loads; land during compute below
            const u16* ks = base + (size_t)((st + 1) * 64 + sr) * 1152 + 64 + sd;
            kr0 = *reinterpret_cast<const uint4*>(ks);
            kr1 = *reinterpret_cast<const uint4*>(ks + 8);
            const u16* vs = base + (size_t)((st + 1) * 64 + sr) * 1152 + 128 + sd;
            vr0 = *reinterpret_cast<const uint4*>(vs);
            vr1 = *reinterpret_cast<const uint4*>(vs + 8);
        }

        f32x4 acc_s[4] = {};
#pragma unroll
        for (int ni = 0; ni < 4; ++ni) {
            bf16x8 bk0 = *reinterpret_cast<const bf16x8*>(&Ks[ni * 16 + r16][quad * 8]);
            bf16x8 bk1 = *reinterpret_cast<const bf16x8*>(&Ks[ni * 16 + r16][32 + quad * 8]);
            acc_s[ni] = __builtin_amdgcn_mfma_f32_16x16x32_bf16(aq0, bk0, acc_s[ni], 0, 0, 0);
            acc_s[ni] = __builtin_amdgcn_mfma_f32_16x16x32_bf16(aq1, bk1, acc_s[ni], 0, 0, 0);
        }

        float sc[4][4];
        float mt[4] = {-3.0e38f, -3.0e38f, -3.0e38f, -3.0e38f};
#pragma unroll
        for (int ni = 0; ni < 4; ++ni)
#pragma unroll
            for (int reg = 0; reg < 4; ++reg) {
                int col = st * 64 + ni * 16 + r16;
                int row = t0 + w * 16 + quad * 4 + reg;
                float v = (col <= row) ? acc_s[ni][reg] * 0.125f : -3.0e38f;
                sc[ni][reg] = v;
                mt[reg] = fmaxf(mt[reg], v);
            }
#pragma unroll
        for (int reg = 0; reg < 4; ++reg) {
#pragma unroll
            for (int off = 1; off <= 8; off <<= 1)
                mt[reg] = fmaxf(mt[reg], __shfl_xor(mt[reg], off, 64));
        }
        float alpha[4], lt[4];
#pragma unroll
        for (int reg = 0; reg < 4; ++reg) {
            float m_new = fmaxf(m_run[reg], mt[reg]);
            alpha[reg] = __expf(m_run[reg] - m_new);
            m_run[reg] = m_new;
            lt[reg] = 0.f;
        }
#pragma unroll
        for (int ni = 0; ni < 4; ++ni)
#pragma unroll
            for (int reg = 0; reg < 4; ++reg) {
                float p = __expf(sc[ni][reg] - m_run[reg]);
                lt[reg] += p;
                Ps[w][quad * 4 + reg][ni * 16 + r16] = f2b(p);
            }
#pragma unroll
        for (int reg = 0; reg < 4; ++reg) {
#pragma unroll
            for (int off = 1; off <= 8; off <<= 1)
                lt[reg] += __shfl_xor(lt[reg], off, 64);
            l_run[reg] = l_run[reg] * alpha[reg] + lt[reg];
        }
#pragma unroll
        for (int ni = 0; ni < 4; ++ni)
#pragma unroll
            for (int reg = 0; reg < 4; ++reg) acc_o[ni][reg] *= alpha[reg];
        __syncthreads();

        bf16x8 ap0 = *reinterpret_cast<const bf16x8*>(&Ps[w][r16][quad * 8]);
        bf16x8 ap1 = *reinterpret_cast<const bf16x8*>(&Ps[w][r16][32 + quad * 8]);
#pragma unroll
        for (int ni = 0; ni < 4; ++ni) {
            int vrow = ni * 16 + r16;
            int vx = (vrow >> 3) & 7;
            bf16x8 bv0 = *reinterpret_cast<const bf16x8*>(
                &Vt[vrow][(quad ^ vx) * 8]);
            bf16x8 bv1 = *reinterpret_cast<const bf16x8*>(
                &Vt[vrow][((quad + 4) ^ vx) * 8]);
            acc_o[ni] = __builtin_amdgcn_mfma_f32_16x16x32_bf16(ap0, bv0, acc_o[ni], 0, 0, 0);
            acc_o[ni] = __builtin_amdgcn_mfma_f32_16x16x32_bf16(ap1, bv1, acc_o[ni], 0, 0, 0);
        }
    }

    float inv[4];
#pragma unroll
    for (int reg = 0; reg < 4; ++reg) inv[reg] = 1.0f / l_run[reg];
#pragma unroll
    for (int ni = 0; ni < 4; ++ni)
#pragma unroll
        for (int reg = 0; reg < 4; ++reg) {
            int t = t0 + w * 16 + quad * 4 + reg;
            o[((size_t)b * Tc + t) * Ec + h * 64 + ni * 16 + r16] =
                f2b(acc_o[ni][reg] * inv[reg]);
        }
}

#define GRD(n) dim3(((n) + 255) / 256)

extern "C" void kernel_launch(void* const* d_in, const int* in_sizes, int n_in,
                              void* d_out, int out_size, void* d_ws, size_t ws_size,
                              hipStream_t stream) {
    const int* ctx = (const int*)d_in[0];
    const float* tok = (const float*)d_in[1];
    const float* pos = (const float*)d_in[2];
    const float* ln1g = (const float*)d_in[3];
    const float* ln1b = (const float*)d_in[4];
    const float* wqkv = (const float*)d_in[5];
    const float* wproj = (const float*)d_in[6];
    const float* bproj = (const float*)d_in[7];
    const float* ln2g = (const float*)d_in[8];
    const float* ln2b = (const float*)d_in[9];
    const float* w1 = (const float*)d_in[10];
    const float* b1 = (const float*)d_in[11];
    const float* w2 = (const float*)d_in[12];
    const float* b2 = (const float*)d_in[13];
    const float* lnfg = (const float*)d_in[14];
    const float* lnfb = (const float*)d_in[15];
    const float* whead = (const float*)d_in[16];
    const float* bhead = (const float*)d_in[17];
    float* out = (float*)d_out;

    // ---- workspace layout --------------------------------------------------
    char* ws = (char*)d_ws;
    float* x = (float*)ws;
    size_t off = (size_t)Mc * Ec * 4;                      // 50.3 MB
    u16* wqkvT = (u16*)(ws + off); off += (size_t)Lc * 1152 * 384 * 2;
    u16* wprojT = (u16*)(ws + off); off += (size_t)Lc * 384 * 384 * 2;
    u16* w1T = (u16*)(ws + off); off += (size_t)Lc * 1536 * 384 * 2;
    u16* w2T = (u16*)(ws + off); off += (size_t)Lc * 384 * 1536 * 2;
    u16* wheadT = (u16*)(ws + off); off += (size_t)128 * 384 * 2;  // padded
    const size_t per_b = (size_t)Tc * (Ec + 1152 + Ec + FFc) * 2;  // 1.77 MB
    if (ws_size < off + per_b) {
        poison_kernel<<<GRD(out_size), 256, 0, stream>>>(out, out_size, 200.0f);
        return;
    }
    int CB = (int)((ws_size - off) / per_b);
    if (CB > Bc) CB = Bc;
    u16* xn_c = (u16*)(ws + off);
    u16* qkv_c = xn_c + (size_t)CB * Tc * Ec;
    u16* o_c = qkv_c + (size_t)CB * Tc * 1152;
    u16* ff_c = o_c + (size_t)CB * Tc * Ec;

    // ---- weight transposes (bf16) -----------------------------------------
    trans_qkv_kernel<<<GRD(Lc * Hc * Ec * 192), 256, 0, stream>>>(wqkv, wqkvT);
    trans_w_kernel<<<GRD(Lc * Ec * Ec), 256, 0, stream>>>(wproj, wprojT, Ec, Ec);
    trans_w_kernel<<<GRD(Lc * Ec * FFc), 256, 0, stream>>>(w1, w1T, Ec, FFc);
    trans_w_kernel<<<GRD(Lc * FFc * Ec), 256, 0, stream>>>(w2, w2T, FFc, Ec);
    hipMemsetAsync(wheadT, 0, (size_t)128 * 384 * 2, stream);
    trans_head_kernel<<<GRD(Ec * Vc), 256, 0, stream>>>(whead, wheadT);

    embed_kernel<<<GRD(Mc * 96), 256, 0, stream>>>(ctx, tok, pos, x);

    for (int l = 0; l < Lc; ++l) {
        for (int b0 = 0; b0 < Bc; b0 += CB) {
            int bcnt = (Bc - b0 < CB) ? (Bc - b0) : CB;
            int rows = bcnt * Tc;
            float* xc = x + (size_t)b0 * Tc * Ec;
            ln_kernel<<<rows / 4, 256, 0, stream>>>(
                xc, xn_c, ln1g + l * Ec, ln1b + l * Ec, rows);
            mfma_gemm<false, false, true, true, true, 512><<<dim3(1152 / 128, rows / 256), 512, 0, stream>>>(
                xn_c, wqkvT + (size_t)l * 1152 * 384, nullptr, nullptr, qkv_c,
                384, 1152, 1152);
            attn_kernel<<<dim3(Tc / 64, Hc, bcnt), 256, 0, stream>>>(qkv_c, o_c);
            mfma_gemm<false, true, false, true, true, 512><<<dim3(Ec / 128, rows / 256), 512, 0, stream>>>(
                o_c, wprojT + (size_t)l * 384 * 384, bproj + l * Ec, xc, xc,
                384, Ec, Ec);
            ln_kernel<<<rows / 4, 256, 0, stream>>>(
                xc, xn_c, ln2g + l * Ec, ln2b + l * Ec, rows);
            mfma_gemm<true, false, true, true, true, 512><<<dim3(FFc / 128, rows / 256), 512, 0, stream>>>(
                xn_c, w1T + (size_t)l * 1536 * 384, b1 + l * FFc, nullptr, ff_c,
                384, FFc, FFc);
            mfma_gemm<false, true, false, true, true, 512><<<dim3(Ec / 128, rows / 256), 512, 0, stream>>>(
                ff_c, w2T + (size_t)l * 384 * 1536, b2 + l * Ec, xc, xc,
                1536, Ec, Ec);
        }
    }
    for (int b0 = 0; b0 < Bc; b0 += CB) {
        int bcnt = (Bc - b0 < CB) ? (Bc - b0) : CB;
        int rows = bcnt * Tc;
        float* xc = x + (size_t)b0 * Tc * Ec;
        ln_kernel<<<rows / 4, 256, 0, stream>>>(xc, xn_c, lnfg, lnfb, rows);
        mfma_gemm<false, false, false, false, false, 256><<<dim3(1, rows / 128), 256, 0, stream>>>(
            xn_c, wheadT, bhead, nullptr, out + (size_t)b0 * Tc * Vc,
            384, Vc, Vc);
    }
}

// Round 17
// 2141.695 us; speedup vs baseline: 1.1106x; 1.1106x over previous
//
#include <hip/hip_runtime.h>

// ---------------------------------------------------------------------------
// ROUND 29 = REVERT to r25 (best measured: 2144.2 us). PIPE3 one-barrier
// loop + setprio on all main GEMMs; operand-swapped epilogues (bf16 via
// swizzled-LDS b128 stores, fp32 direct f32x4); attn with reg-prefetch +
// Vt XOR-swizzle; vectorized LN/embed. r28's 256x128 tile regressed (+11%:
// 2 blocks/CU residency loss > arithmetic-intensity gain) — 128x128/4-wave
// confirmed as this structure's optimum. Session: 3070 -> ~2145 us.
// fp32 residual/output. B=128 T=256 E=384 H=6 HS=64 L=6 V=78 FF=1536.
// ---------------------------------------------------------------------------

#define Bc 128
#define Tc 256
#define Ec 384
#define Hc 6
#define HSc 64
#define Lc 6
#define Vc 78
#define FFc 1536
#define Mc (Bc * Tc)  // 32768 tokens

typedef unsigned short u16;
using bf16x8 = __attribute__((ext_vector_type(8))) short;
using f32x4 = __attribute__((ext_vector_type(4))) float;

__device__ __forceinline__ float b2f(u16 u) {
    union { float f; unsigned int i; } x;
    x.i = ((unsigned int)u) << 16;
    return x.f;
}
__device__ __forceinline__ u16 f2b(float f) {
    union { float f; unsigned int u; } x;
    x.f = f;
    unsigned int r = x.u + 0x7fffu + ((x.u >> 16) & 1u);  // RNE
    return (u16)(r >> 16);
}

// async global->LDS, 16B per lane; dest is wave-uniform base + lane*16
__device__ __forceinline__ void gload_lds16(const u16* g, u16* l) {
    __builtin_amdgcn_global_load_lds(
        (const __attribute__((address_space(1))) unsigned int*)g,
        (__attribute__((address_space(3))) unsigned int*)l, 16, 0, 0);
}

__global__ __launch_bounds__(256) void poison_kernel(
    float* __restrict__ out, int n, float val) {
    int i = blockIdx.x * 256 + threadIdx.x;
    if (i < n) out[i] = val;
}

// --- weight pre-transpose to bf16 [N][K] ------------------------------------
__global__ __launch_bounds__(256) void trans_qkv_kernel(
    const float* __restrict__ in, u16* __restrict__ out) {
    int i = blockIdx.x * 256 + threadIdx.x;  // < L*H*E*192
    if (i >= Lc * Hc * Ec * 192) return;
    int f = i % 192;
    int r = i / 192;
    int e = r % Ec; r /= Ec;
    int h = r % Hc;
    int l = r / Hc;
    out[((size_t)l * 1152 + h * 192 + f) * Ec + e] = f2b(in[i]);
}
__global__ __launch_bounds__(256) void trans_w_kernel(
    const float* __restrict__ in, u16* __restrict__ out, int K, int N) {
    int i = blockIdx.x * 256 + threadIdx.x;  // < L*K*N
    if (i >= Lc * K * N) return;
    int n = i % N;
    int r = i / N;
    int k = r % K;
    int l = r / K;
    out[((size_t)l * N + n) * K + k] = f2b(in[i]);
}
// head: in[e*Vc+v] -> out[v*Ec+e], v<Vc (rows Vc..127 pre-zeroed)
__global__ __launch_bounds__(256) void trans_head_kernel(
    const float* __restrict__ in, u16* __restrict__ out) {
    int i = blockIdx.x * 256 + threadIdx.x;  // < Ec*Vc
    if (i >= Ec * Vc) return;
    int v = i % Vc, e = i / Vc;
    out[(size_t)v * Ec + e] = f2b(in[i]);
}

// --- x[bt,e4] = tok_emb[ctx[bt],e4] + pos_emb[t,e4]  (fp32, f32x4) ----------
__global__ __launch_bounds__(256) void embed_kernel(
    const int* __restrict__ ctx, const float* __restrict__ tok,
    const float* __restrict__ pos, float* __restrict__ x) {
    int i = blockIdx.x * 256 + threadIdx.x;  // over Mc*96
    if (i >= Mc * 96) return;
    int c4 = (i % 96) * 4, bt = i / 96, t = bt % Tc;
    f32x4 tv = *reinterpret_cast<const f32x4*>(&tok[ctx[bt] * Ec + c4]);
    f32x4 pv = *reinterpret_cast<const f32x4*>(&pos[t * Ec + c4]);
    *reinterpret_cast<f32x4*>(&x[(size_t)bt * Ec + c4]) = tv + pv;
}

// --- layernorm fp32 in -> bf16 out: one wave per row (float2/ushort2) -------
__global__ __launch_bounds__(256) void ln_kernel(
    const float* __restrict__ X, u16* __restrict__ Y,
    const float* __restrict__ g, const float* __restrict__ b, int nrows) {
    int row = blockIdx.x * 4 + (threadIdx.x >> 6);
    int lane = threadIdx.x & 63;
    if (row >= nrows) return;
    const float* xr = X + (size_t)row * Ec;
    float2 v[3];
    float s = 0.f;
#pragma unroll
    for (int i = 0; i < 3; ++i) {
        v[i] = *reinterpret_cast<const float2*>(&xr[2 * lane + 128 * i]);
        s += v[i].x + v[i].y;
    }
#pragma unroll
    for (int off = 32; off >= 1; off >>= 1) s += __shfl_xor(s, off, 64);
    float mean = s * (1.0f / Ec);
    float s2 = 0.f;
#pragma unroll
    for (int i = 0; i < 3; ++i) {
        float dx = v[i].x - mean, dy = v[i].y - mean;
        s2 += dx * dx + dy * dy;
    }
#pragma unroll
    for (int off = 32; off >= 1; off >>= 1) s2 += __shfl_xor(s2, off, 64);
    float rstd = rsqrtf(s2 * (1.0f / Ec) + 1e-5f);
    u16* yr = Y + (size_t)row * Ec;
#pragma unroll
    for (int i = 0; i < 3; ++i) {
        int e = 2 * lane + 128 * i;
        float2 gv = *reinterpret_cast<const float2*>(&g[e]);
        float2 bv = *reinterpret_cast<const float2*>(&b[e]);
        ushort2 ov;
        ov.x = f2b((v[i].x - mean) * rstd * gv.x + bv.x);
        ov.y = f2b((v[i].y - mean) * rstd * gv.y + bv.y);
        *reinterpret_cast<ushort2*>(&yr[e]) = ov;
    }
}

// --- MFMA GEMM: C[*, ldC] = A[M,K](bf16) @ Wt[N,K]^T(bf16) [+bias][+R] ------
// 128x128 tile, 4 waves (2x2 of 64x64).
// PIPE3=false: r13 loop (BK=64, single 32KB buffer, 2 drains/tile).
// PIPE3=true : BK=32, TRIPLE buffer (48KB), counted vmcnt(4), depth-2
//   prefetch, ONE barrier/tile: per-wave vmcnt(4) + barrier proves tile t
//   visible AND buf (t+2)%3 free -> stage3(t+2) issues BEFORE compute3(t).
//   setprio(1) around compute cluster. Involution: 16B slot
//   p = s ^ ((row>>1)&3); source pre-swizzle (l&3)^((l>>3)&3); read
//   csw = quad ^ ((r16>>1)&3). K%32==0, K/32>=3.
// SWAP = VECEPI: operand-swapped mfma -> acc[mi][ni] = 4 consecutive n
//   (base n0+wn+ni*16+quad*4) of row m0+wm+mi*16+r16 (r18-verified layout).
// Epilogues (NV % 128 == 0 required for VECEPI):
//   VECEPI && OUTBF16 : f32x4 bias -> 16x ushort4 swizzled LDS writes ->
//                       8x b128 coalesced global stores.
//   VECEPI && !OUTBF16: direct f32x4 bias/R/store, no LDS.
//   !VECEPI           : scalar epilogue with NV guard (head GEMM).
template <bool RELU, bool RESID, bool OUTBF16, bool VECEPI, bool PIPE3>
__global__ __launch_bounds__(256) void mfma_gemm(
    const u16* __restrict__ A, const u16* __restrict__ Wt,
    const float* __restrict__ bias, const float* R, void* C,
    int K, int ldC, int NV) {
    constexpr bool SWAP = VECEPI;
    __shared__ __align__(16) u16 smem[PIPE3 ? 24576 : 16384];
    int tid = threadIdx.x;

    // bijective XCD swizzle (m204): contiguous bid chunk per XCD
    int nwg = gridDim.x * gridDim.y;
    int bid = blockIdx.y * gridDim.x + blockIdx.x;
    int q = nwg >> 3, r = nwg & 7;
    int xcd = bid & 7, idx = bid >> 3;
    int swz = (xcd < r ? xcd * (q + 1) : r * (q + 1) + (xcd - r) * q) + idx;
    int bx = swz % gridDim.x, by = swz / gridDim.x;
    int m0 = by * 128, n0 = bx * 128;

    int w = tid >> 6, lane = tid & 63;
    int wm = (w >> 1) * 64, wn = (w & 1) * 64;
    int r16 = lane & 15, quad = lane >> 4;

    f32x4 acc[4][4] = {};

    if constexpr (PIPE3) {
        u16(*As3)[128][32] = (u16(*)[128][32])smem;
        u16(*Bs3)[128][32] = (u16(*)[128][32])(smem + 3 * 128 * 32);
        // wave w stages chunks {2w, 2w+1}; chunk c = rows 16c..16c+15.
        // lane l -> row 16c + (l>>2), physical slot l&3,
        // source col slot = (l&3) ^ ((l>>3)&3).
        int rA = 2 * w * 16 + (lane >> 2);
        int colsw = ((lane & 3) ^ ((lane >> 3) & 3)) * 8;
        const u16* a0 = A + (size_t)(m0 + rA) * K + colsw;
        const u16* a1 = A + (size_t)(m0 + rA + 16) * K + colsw;
        const u16* b0 = Wt + (size_t)(n0 + rA) * K + colsw;
        const u16* b1 = Wt + (size_t)(n0 + rA + 16) * K + colsw;

        auto stage3 = [&](int buf, int t) {
            int k0 = t * 32;
            gload_lds16(a0 + k0, &As3[buf][2 * w * 16][0]);
            gload_lds16(a1 + k0, &As3[buf][2 * w * 16 + 16][0]);
            gload_lds16(b0 + k0, &Bs3[buf][2 * w * 16][0]);
            gload_lds16(b1 + k0, &Bs3[buf][2 * w * 16 + 16][0]);
        };
        int csw = (quad ^ ((r16 >> 1) & 3)) * 8;
        auto compute3 = [&](int buf) {
            bf16x8 af[4], bf[4];
#pragma unroll
            for (int i = 0; i < 4; ++i) {
                af[i] = *reinterpret_cast<const bf16x8*>(
                    &As3[buf][wm + i * 16 + r16][csw]);
                bf[i] = *reinterpret_cast<const bf16x8*>(
                    &Bs3[buf][wn + i * 16 + r16][csw]);
            }
#pragma unroll
            for (int mi = 0; mi < 4; ++mi)
#pragma unroll
                for (int ni = 0; ni < 4; ++ni) {
                    if (SWAP)
                        acc[mi][ni] = __builtin_amdgcn_mfma_f32_16x16x32_bf16(
                            bf[ni], af[mi], acc[mi][ni], 0, 0, 0);
                    else
                        acc[mi][ni] = __builtin_amdgcn_mfma_f32_16x16x32_bf16(
                            af[mi], bf[ni], acc[mi][ni], 0, 0, 0);
                }
        };

        int nt = K >> 5;  // >= 3 required
        stage3(0, 0);
        stage3(1, 1);
        int buf = 0;
        for (int t = 0; t < nt - 1; ++t) {
            // per-wave: tile-t loads landed (oldest 4 of 8 outstanding)
            asm volatile("s_waitcnt vmcnt(4)" ::: "memory");
            // all waves: tile t visible; buf (t+2)%3 done being read
            __builtin_amdgcn_s_barrier();
            __builtin_amdgcn_sched_barrier(0);
            if (t + 2 < nt) {  // issue next-next tile BEFORE compute
                int b2 = buf + 2;
                if (b2 >= 3) b2 -= 3;
                stage3(b2, t + 2);
            }
            __builtin_amdgcn_s_setprio(1);
            compute3(buf);
            __builtin_amdgcn_s_setprio(0);
            buf = (buf == 2) ? 0 : buf + 1;
        }
        asm volatile("s_waitcnt vmcnt(0)" ::: "memory");  // last tile landed
        __builtin_amdgcn_s_barrier();
        __builtin_amdgcn_sched_barrier(0);
        compute3(buf);
    } else {
        u16(*As)[64] = (u16(*)[64])smem;
        u16(*Bs)[64] = (u16(*)[64])(smem + 128 * 64);
        // staging geometry: wave w owns 1KB chunks {4w..4w+3} of each tile.
        // chunk c covers rows c*8..c*8+7; lane l -> row c*8 + (l>>3),
        // physical 8-elem slot (l&7); source col chunk = (l&7) ^ (l>>3).
        int lrow = lane >> 3;
        int scol = ((lane & 7) ^ lrow) * 8;
        const u16* ap[4];
        const u16* bp[4];
#pragma unroll
        for (int j = 0; j < 4; ++j) {
            int row = (w * 4 + j) * 8 + lrow;
            ap[j] = A + (size_t)(m0 + row) * K + scol;
            bp[j] = Wt + (size_t)(n0 + row) * K + scol;
        }
        for (int k0 = 0; k0 < K; k0 += 64) {
            __syncthreads();
#pragma unroll
            for (int j = 0; j < 4; ++j) {
                gload_lds16(ap[j], &As[(w * 4 + j) * 8][0]);
                gload_lds16(bp[j], &Bs[(w * 4 + j) * 8][0]);
                ap[j] += 64;
                bp[j] += 64;
            }
            __syncthreads();
#pragma unroll
            for (int kk = 0; kk < 2; ++kk) {
                int csw = ((kk * 4 + quad) ^ (r16 & 7)) * 8;  // swizzled col
                bf16x8 af[4], bf[4];
#pragma unroll
                for (int i = 0; i < 4; ++i) {
                    af[i] = *reinterpret_cast<const bf16x8*>(
                        &As[wm + i * 16 + r16][csw]);
                    bf[i] = *reinterpret_cast<const bf16x8*>(
                        &Bs[wn + i * 16 + r16][csw]);
                }
#pragma unroll
                for (int mi = 0; mi < 4; ++mi)
#pragma unroll
                    for (int ni = 0; ni < 4; ++ni) {
                        if (SWAP)
                            acc[mi][ni] = __builtin_amdgcn_mfma_f32_16x16x32_bf16(
                                bf[ni], af[mi], acc[mi][ni], 0, 0, 0);
                        else
                            acc[mi][ni] = __builtin_amdgcn_mfma_f32_16x16x32_bf16(
                                af[mi], bf[ni], acc[mi][ni], 0, 0, 0);
                    }
            }
        }
    }

    // ---- epilogue ----------------------------------------------------------
    if (VECEPI && OUTBF16) {
        // swapped layout: acc[mi][ni] = 4 consecutive n (gn..gn+3) of row
        // m0+wm+mi*16+r16, gn = n0+wn+ni*16+quad*4.
        f32x4 bv4[4];
#pragma unroll
        for (int ni = 0; ni < 4; ++ni) {
            int gn = n0 + wn + ni * 16 + quad * 4;
            if (bias)
                bv4[ni] = *reinterpret_cast<const f32x4*>(&bias[gn]);
            else
                bv4[ni] = f32x4{0.f, 0.f, 0.f, 0.f};
        }
        __syncthreads();  // main-loop LDS reads done
        // write: [128][128] u16, 8-elem chunk swizzled pc = cc ^ (row&15);
        // one ushort4 (8B) write per (mi,ni) at half (quad&1) of chunk.
#pragma unroll
        for (int mi = 0; mi < 4; ++mi) {
            int row = wm + mi * 16 + r16;
#pragma unroll
            for (int ni = 0; ni < 4; ++ni) {
                int colb = wn + ni * 16 + quad * 4;
                f32x4 v = acc[mi][ni] + bv4[ni];
                if (RELU) {
#pragma unroll
                    for (int e = 0; e < 4; ++e) v[e] = fmaxf(v[e], 0.f);
                }
                ushort4 ov;
                ov.x = f2b(v[0]);
                ov.y = f2b(v[1]);
                ov.z = f2b(v[2]);
                ov.w = f2b(v[3]);
                int pc = (colb >> 3) ^ (row & 15);
                *reinterpret_cast<ushort4*>(
                    &smem[row * 128 + pc * 8 + (colb & 7)]) = ov;
            }
        }
        __syncthreads();
        // read + store: thread t -> rows (t>>3)+32i, chunk (t&7)+8h
        u16* cp = (u16*)C;
#pragma unroll
        for (int i = 0; i < 4; ++i) {
            int row = (tid >> 3) + 32 * i;
#pragma unroll
            for (int h = 0; h < 2; ++h) {
                int lc = (tid & 7) + 8 * h;
                int pc = lc ^ (row & 15);
                bf16x8 val = *reinterpret_cast<const bf16x8*>(
                    &smem[row * 128 + pc * 8]);
                *reinterpret_cast<bf16x8*>(
                    &cp[(size_t)(m0 + row) * ldC + n0 + lc * 8]) = val;
            }
        }
    } else if (VECEPI) {
        // operand-swapped fp32 path: direct f32x4 bias/R/store.
        float* cp = (float*)C;
        f32x4 bv4[4];
#pragma unroll
        for (int ni = 0; ni < 4; ++ni) {
            int gn = n0 + wn + ni * 16 + quad * 4;
            if (bias)
                bv4[ni] = *reinterpret_cast<const f32x4*>(&bias[gn]);
            else
                bv4[ni] = f32x4{0.f, 0.f, 0.f, 0.f};
        }
#pragma unroll
        for (int mi = 0; mi < 4; ++mi) {
            int gm = m0 + wm + mi * 16 + r16;
#pragma unroll
            for (int ni = 0; ni < 4; ++ni) {
                int gn = n0 + wn + ni * 16 + quad * 4;
                size_t goff = (size_t)gm * ldC + gn;
                f32x4 v = acc[mi][ni] + bv4[ni];
                if (RELU) {
#pragma unroll
                    for (int e = 0; e < 4; ++e) v[e] = fmaxf(v[e], 0.f);
                }
                if (RESID) v += *reinterpret_cast<const f32x4*>(&R[goff]);
                *reinterpret_cast<f32x4*>(&cp[goff]) = v;
            }
        }
    } else {
        // scalar epilogue with NV guard (head GEMM; unswapped layout)
#pragma unroll
        for (int mi = 0; mi < 4; ++mi)
#pragma unroll
            for (int ni = 0; ni < 4; ++ni) {
                int gn = n0 + wn + ni * 16 + r16;
                if (gn >= NV) continue;
                float bvs = bias ? bias[gn] : 0.f;
#pragma unroll
                for (int reg = 0; reg < 4; ++reg) {
                    int gm = m0 + wm + mi * 16 + quad * 4 + reg;
                    float v = acc[mi][ni][reg] + bvs;
                    if (RESID) v += R[(size_t)gm * ldC + gn];
                    if (RELU) v = fmaxf(v, 0.f);
                    if (OUTBF16)
                        ((u16*)C)[(size_t)gm * ldC + gn] = f2b(v);
                    else
                        ((float*)C)[(size_t)gm * ldC + gn] = v;
                }
            }
    }
}

// --- MFMA flash attention: T14 reg-prefetch + Vt XOR-swizzle (r24) ----------
// Vt store: logical col t=sr of row d lands at chunk (sr>>3)^((d>>3)&7),
// slot sr&7. Read of logical chunk q: physical q^((d>>3)&7). 8-way -> 2-way.
__global__ __launch_bounds__(256) void attn_kernel(
    const u16* __restrict__ qkv, u16* __restrict__ o) {
    __shared__ u16 Qs[64][72];
    __shared__ u16 Ks[64][72];
    __shared__ u16 Vt[64][72];
    __shared__ u16 Ps[4][16][72];
    int tid = threadIdx.x;
    int tt = blockIdx.x, h = blockIdx.y, b = blockIdx.z;
    int w = tid >> 6, lane = tid & 63;
    int r16 = lane & 15, quad = lane >> 4;
    int t0 = tt * 64;
    const u16* base = qkv + (size_t)b * Tc * 1152 + h * 192;

    int sr = tid >> 2, sd = (tid & 3) * 16;
    {
        const u16* src = base + (size_t)(t0 + sr) * 1152 + sd;
        *reinterpret_cast<uint4*>(&Qs[sr][sd]) =
            *reinterpret_cast<const uint4*>(src);
        *reinterpret_cast<uint4*>(&Qs[sr][sd + 8]) =
            *reinterpret_cast<const uint4*>(src + 8);
    }
    __syncthreads();
    // hoisted Q fragments (loop-invariant; compiler can't hoist across barriers)
    bf16x8 aq0 = *reinterpret_cast<const bf16x8*>(&Qs[w * 16 + r16][quad * 8]);
    bf16x8 aq1 = *reinterpret_cast<const bf16x8*>(&Qs[w * 16 + r16][32 + quad * 8]);

    // prefetch tile 0 K/V into registers
    uint4 kr0, kr1, vr0, vr1;
    {
        const u16* ks = base + (size_t)sr * 1152 + 64 + sd;
        kr0 = *reinterpret_cast<const uint4*>(ks);
        kr1 = *reinterpret_cast<const uint4*>(ks + 8);
        const u16* vs = base + (size_t)sr * 1152 + 128 + sd;
        vr0 = *reinterpret_cast<const uint4*>(vs);
        vr1 = *reinterpret_cast<const uint4*>(vs + 8);
    }
    int vslot = sr & 7, vchk = sr >> 3;  // for swizzled Vt store

    float m_run[4], l_run[4];
#pragma unroll
    for (int r = 0; r < 4; ++r) { m_run[r] = -3.0e38f; l_run[r] = 0.f; }
    f32x4 acc_o[4] = {};

    for (int st = 0; st <= tt; ++st) {
        __syncthreads();  // prev reads of Ks/Vt done
        {
            *reinterpret_cast<uint4*>(&Ks[sr][sd]) = kr0;
            *reinterpret_cast<uint4*>(&Ks[sr][sd + 8]) = kr1;
            u16 tv[16];
            *reinterpret_cast<uint4*>(tv) = vr0;
            *reinterpret_cast<uint4*>(tv + 8) = vr1;
#pragma unroll
            for (int j = 0; j < 16; ++j) {
                int row = sd + j;
                int pc = vchk ^ ((row >> 3) & 7);
                Vt[row][pc * 8 + vslot] = tv[j];
            }
        }
        __syncthreads();  // staged tile visible
        if (st < tt) {  // issue next-tile loads; land during compute below
            const u16* ks = base + (size_t)((st + 1) * 64 + sr) * 1152 + 64 + sd;
            kr0 = *reinterpret_cast<const uint4*>(ks);
            kr1 = *reinterpret_cast<const uint4*>(ks + 8);
            const u16* vs = base + (size_t)((st + 1) * 64 + sr) * 1152 + 128 + sd;
            vr0 = *reinterpret_cast<const uint4*>(vs);
            vr1 = *reinterpret_cast<const uint4*>(vs + 8);
        }

        f32x4 acc_s[4] = {};
#pragma unroll
        for (int ni = 0; ni < 4; ++ni) {
            bf16x8 bk0 = *reinterpret_cast<const bf16x8*>(&Ks[ni * 16 + r16][quad * 8]);
            bf16x8 bk1 = *reinterpret_cast<const bf16x8*>(&Ks[ni * 16 + r16][32 + quad * 8]);
            acc_s[ni] = __builtin_amdgcn_mfma_f32_16x16x32_bf16(aq0, bk0, acc_s[ni], 0, 0, 0);
            acc_s[ni] = __builtin_amdgcn_mfma_f32_16x16x32_bf16(aq1, bk1, acc_s[ni], 0, 0, 0);
        }

        float sc[4][4];
        float mt[4] = {-3.0e38f, -3.0e38f, -3.0e38f, -3.0e38f};
#pragma unroll
        for (int ni = 0; ni < 4; ++ni)
#pragma unroll
            for (int reg = 0; reg < 4; ++reg) {
                int col = st * 64 + ni * 16 + r16;
                int row = t0 + w * 16 + quad * 4 + reg;
                float v = (col <= row) ? acc_s[ni][reg] * 0.125f : -3.0e38f;
                sc[ni][reg] = v;
                mt[reg] = fmaxf(mt[reg], v);
            }
#pragma unroll
        for (int reg = 0; reg < 4; ++reg) {
#pragma unroll
            for (int off = 1; off <= 8; off <<= 1)
                mt[reg] = fmaxf(mt[reg], __shfl_xor(mt[reg], off, 64));
        }
        float alpha[4], lt[4];
#pragma unroll
        for (int reg = 0; reg < 4; ++reg) {
            float m_new = fmaxf(m_run[reg], mt[reg]);
            alpha[reg] = __expf(m_run[reg] - m_new);
            m_run[reg] = m_new;
            lt[reg] = 0.f;
        }
#pragma unroll
        for (int ni = 0; ni < 4; ++ni)
#pragma unroll
            for (int reg = 0; reg < 4; ++reg) {
                float p = __expf(sc[ni][reg] - m_run[reg]);
                lt[reg] += p;
                Ps[w][quad * 4 + reg][ni * 16 + r16] = f2b(p);
            }
#pragma unroll
        for (int reg = 0; reg < 4; ++reg) {
#pragma unroll
            for (int off = 1; off <= 8; off <<= 1)
                lt[reg] += __shfl_xor(lt[reg], off, 64);
            l_run[reg] = l_run[reg] * alpha[reg] + lt[reg];
        }
#pragma unroll
        for (int ni = 0; ni < 4; ++ni)
#pragma unroll
            for (int reg = 0; reg < 4; ++reg) acc_o[ni][reg] *= alpha[reg];
        __syncthreads();

        bf16x8 ap0 = *reinterpret_cast<const bf16x8*>(&Ps[w][r16][quad * 8]);
        bf16x8 ap1 = *reinterpret_cast<const bf16x8*>(&Ps[w][r16][32 + quad * 8]);
#pragma unroll
        for (int ni = 0; ni < 4; ++ni) {
            int vrow = ni * 16 + r16;
            int vx = (vrow >> 3) & 7;
            bf16x8 bv0 = *reinterpret_cast<const bf16x8*>(
                &Vt[vrow][(quad ^ vx) * 8]);
            bf16x8 bv1 = *reinterpret_cast<const bf16x8*>(
                &Vt[vrow][((quad + 4) ^ vx) * 8]);
            acc_o[ni] = __builtin_amdgcn_mfma_f32_16x16x32_bf16(ap0, bv0, acc_o[ni], 0, 0, 0);
            acc_o[ni] = __builtin_amdgcn_mfma_f32_16x16x32_bf16(ap1, bv1, acc_o[ni], 0, 0, 0);
        }
    }

    float inv[4];
#pragma unroll
    for (int reg = 0; reg < 4; ++reg) inv[reg] = 1.0f / l_run[reg];
#pragma unroll
    for (int ni = 0; ni < 4; ++ni)
#pragma unroll
        for (int reg = 0; reg < 4; ++reg) {
            int t = t0 + w * 16 + quad * 4 + reg;
            o[((size_t)b * Tc + t) * Ec + h * 64 + ni * 16 + r16] =
                f2b(acc_o[ni][reg] * inv[reg]);
        }
}

#define GRD(n) dim3(((n) + 255) / 256)

extern "C" void kernel_launch(void* const* d_in, const int* in_sizes, int n_in,
                              void* d_out, int out_size, void* d_ws, size_t ws_size,
                              hipStream_t stream) {
    const int* ctx = (const int*)d_in[0];
    const float* tok = (const float*)d_in[1];
    const float* pos = (const float*)d_in[2];
    const float* ln1g = (const float*)d_in[3];
    const float* ln1b = (const float*)d_in[4];
    const float* wqkv = (const float*)d_in[5];
    const float* wproj = (const float*)d_in[6];
    const float* bproj = (const float*)d_in[7];
    const float* ln2g = (const float*)d_in[8];
    const float* ln2b = (const float*)d_in[9];
    const float* w1 = (const float*)d_in[10];
    const float* b1 = (const float*)d_in[11];
    const float* w2 = (const float*)d_in[12];
    const float* b2 = (const float*)d_in[13];
    const float* lnfg = (const float*)d_in[14];
    const float* lnfb = (const float*)d_in[15];
    const float* whead = (const float*)d_in[16];
    const float* bhead = (const float*)d_in[17];
    float* out = (float*)d_out;

    // ---- workspace layout --------------------------------------------------
    char* ws = (char*)d_ws;
    float* x = (float*)ws;
    size_t off = (size_t)Mc * Ec * 4;                      // 50.3 MB
    u16* wqkvT = (u16*)(ws + off); off += (size_t)Lc * 1152 * 384 * 2;
    u16* wprojT = (u16*)(ws + off); off += (size_t)Lc * 384 * 384 * 2;
    u16* w1T = (u16*)(ws + off); off += (size_t)Lc * 1536 * 384 * 2;
    u16* w2T = (u16*)(ws + off); off += (size_t)Lc * 384 * 1536 * 2;
    u16* wheadT = (u16*)(ws + off); off += (size_t)128 * 384 * 2;  // padded
    const size_t per_b = (size_t)Tc * (Ec + 1152 + Ec + FFc) * 2;  // 1.77 MB
    if (ws_size < off + per_b) {
        poison_kernel<<<GRD(out_size), 256, 0, stream>>>(out, out_size, 200.0f);
        return;
    }
    int CB = (int)((ws_size - off) / per_b);
    if (CB > Bc) CB = Bc;
    u16* xn_c = (u16*)(ws + off);
    u16* qkv_c = xn_c + (size_t)CB * Tc * Ec;
    u16* o_c = qkv_c + (size_t)CB * Tc * 1152;
    u16* ff_c = o_c + (size_t)CB * Tc * Ec;

    // ---- weight transposes (bf16) -----------------------------------------
    trans_qkv_kernel<<<GRD(Lc * Hc * Ec * 192), 256, 0, stream>>>(wqkv, wqkvT);
    trans_w_kernel<<<GRD(Lc * Ec * Ec), 256, 0, stream>>>(wproj, wprojT, Ec, Ec);
    trans_w_kernel<<<GRD(Lc * Ec * FFc), 256, 0, stream>>>(w1, w1T, Ec, FFc);
    trans_w_kernel<<<GRD(Lc * FFc * Ec), 256, 0, stream>>>(w2, w2T, FFc, Ec);
    hipMemsetAsync(wheadT, 0, (size_t)128 * 384 * 2, stream);
    trans_head_kernel<<<GRD(Ec * Vc), 256, 0, stream>>>(whead, wheadT);

    embed_kernel<<<GRD(Mc * 96), 256, 0, stream>>>(ctx, tok, pos, x);

    for (int l = 0; l < Lc; ++l) {
        for (int b0 = 0; b0 < Bc; b0 += CB) {
            int bcnt = (Bc - b0 < CB) ? (Bc - b0) : CB;
            int rows = bcnt * Tc;
            float* xc = x + (size_t)b0 * Tc * Ec;
            ln_kernel<<<rows / 4, 256, 0, stream>>>(
                xc, xn_c, ln1g + l * Ec, ln1b + l * Ec, rows);
            mfma_gemm<false, false, true, true, true><<<dim3(1152 / 128, rows / 128), 256, 0, stream>>>(
                xn_c, wqkvT + (size_t)l * 1152 * 384, nullptr, nullptr, qkv_c,
                384, 1152, 1152);
            attn_kernel<<<dim3(Tc / 64, Hc, bcnt), 256, 0, stream>>>(qkv_c, o_c);
            mfma_gemm<false, true, false, true, true><<<dim3(Ec / 128, rows / 128), 256, 0, stream>>>(
                o_c, wprojT + (size_t)l * 384 * 384, bproj + l * Ec, xc, xc,
                384, Ec, Ec);
            ln_kernel<<<rows / 4, 256, 0, stream>>>(
                xc, xn_c, ln2g + l * Ec, ln2b + l * Ec, rows);
            mfma_gemm<true, false, true, true, true><<<dim3(FFc / 128, rows / 128), 256, 0, stream>>>(
                xn_c, w1T + (size_t)l * 1536 * 384, b1 + l * FFc, nullptr, ff_c,
                384, FFc, FFc);
            mfma_gemm<false, true, false, true, true><<<dim3(Ec / 128, rows / 128), 256, 0, stream>>>(
                ff_c, w2T + (size_t)l * 384 * 1536, b2 + l * Ec, xc, xc,
                1536, Ec, Ec);
        }
    }
    for (int b0 = 0; b0 < Bc; b0 += CB) {
        int bcnt = (Bc - b0 < CB) ? (Bc - b0) : CB;
        int rows = bcnt * Tc;
        float* xc = x + (size_t)b0 * Tc * Ec;
        ln_kernel<<<rows / 4, 256, 0, stream>>>(xc, xn_c, lnfg, lnfb, rows);
        mfma_gemm<false, false, false, false, false><<<dim3(1, rows / 128), 256, 0, stream>>>(
            xn_c, wheadT, bhead, nullptr, out + (size_t)b0 * Tc * Vc,
            384, Vc, Vc);
    }
}

// Round 18
// 2138.222 us; speedup vs baseline: 1.1124x; 1.0016x over previous
//
#include <hip/hip_runtime.h>

// ---------------------------------------------------------------------------
// ROUND 30 = r29 + removal of the REDUNDANT 3rd barrier in attn_kernel:
// Ps[4][16][72] is indexed by wave id w on every access (wave-private), so
// the post-softmax __syncthreads() before the PV phase is unnecessary —
// within-wave cross-lane LDS ordering is handled by compiler-inserted
// lgkmcnt (same idiom as ds_swizzle wave reduce). Vt/Ks reads are covered
// by the staging barrier. Everything else identical to r29 (2141.7 us).
// fp32 residual/output. B=128 T=256 E=384 H=6 HS=64 L=6 V=78 FF=1536.
// ---------------------------------------------------------------------------

#define Bc 128
#define Tc 256
#define Ec 384
#define Hc 6
#define HSc 64
#define Lc 6
#define Vc 78
#define FFc 1536
#define Mc (Bc * Tc)  // 32768 tokens

typedef unsigned short u16;
using bf16x8 = __attribute__((ext_vector_type(8))) short;
using f32x4 = __attribute__((ext_vector_type(4))) float;

__device__ __forceinline__ float b2f(u16 u) {
    union { float f; unsigned int i; } x;
    x.i = ((unsigned int)u) << 16;
    return x.f;
}
__device__ __forceinline__ u16 f2b(float f) {
    union { float f; unsigned int u; } x;
    x.f = f;
    unsigned int r = x.u + 0x7fffu + ((x.u >> 16) & 1u);  // RNE
    return (u16)(r >> 16);
}

// async global->LDS, 16B per lane; dest is wave-uniform base + lane*16
__device__ __forceinline__ void gload_lds16(const u16* g, u16* l) {
    __builtin_amdgcn_global_load_lds(
        (const __attribute__((address_space(1))) unsigned int*)g,
        (__attribute__((address_space(3))) unsigned int*)l, 16, 0, 0);
}

__global__ __launch_bounds__(256) void poison_kernel(
    float* __restrict__ out, int n, float val) {
    int i = blockIdx.x * 256 + threadIdx.x;
    if (i < n) out[i] = val;
}

// --- weight pre-transpose to bf16 [N][K] ------------------------------------
__global__ __launch_bounds__(256) void trans_qkv_kernel(
    const float* __restrict__ in, u16* __restrict__ out) {
    int i = blockIdx.x * 256 + threadIdx.x;  // < L*H*E*192
    if (i >= Lc * Hc * Ec * 192) return;
    int f = i % 192;
    int r = i / 192;
    int e = r % Ec; r /= Ec;
    int h = r % Hc;
    int l = r / Hc;
    out[((size_t)l * 1152 + h * 192 + f) * Ec + e] = f2b(in[i]);
}
__global__ __launch_bounds__(256) void trans_w_kernel(
    const float* __restrict__ in, u16* __restrict__ out, int K, int N) {
    int i = blockIdx.x * 256 + threadIdx.x;  // < L*K*N
    if (i >= Lc * K * N) return;
    int n = i % N;
    int r = i / N;
    int k = r % K;
    int l = r / K;
    out[((size_t)l * N + n) * K + k] = f2b(in[i]);
}
// head: in[e*Vc+v] -> out[v*Ec+e], v<Vc (rows Vc..127 pre-zeroed)
__global__ __launch_bounds__(256) void trans_head_kernel(
    const float* __restrict__ in, u16* __restrict__ out) {
    int i = blockIdx.x * 256 + threadIdx.x;  // < Ec*Vc
    if (i >= Ec * Vc) return;
    int v = i % Vc, e = i / Vc;
    out[(size_t)v * Ec + e] = f2b(in[i]);
}

// --- x[bt,e4] = tok_emb[ctx[bt],e4] + pos_emb[t,e4]  (fp32, f32x4) ----------
__global__ __launch_bounds__(256) void embed_kernel(
    const int* __restrict__ ctx, const float* __restrict__ tok,
    const float* __restrict__ pos, float* __restrict__ x) {
    int i = blockIdx.x * 256 + threadIdx.x;  // over Mc*96
    if (i >= Mc * 96) return;
    int c4 = (i % 96) * 4, bt = i / 96, t = bt % Tc;
    f32x4 tv = *reinterpret_cast<const f32x4*>(&tok[ctx[bt] * Ec + c4]);
    f32x4 pv = *reinterpret_cast<const f32x4*>(&pos[t * Ec + c4]);
    *reinterpret_cast<f32x4*>(&x[(size_t)bt * Ec + c4]) = tv + pv;
}

// --- layernorm fp32 in -> bf16 out: one wave per row (float2/ushort2) -------
__global__ __launch_bounds__(256) void ln_kernel(
    const float* __restrict__ X, u16* __restrict__ Y,
    const float* __restrict__ g, const float* __restrict__ b, int nrows) {
    int row = blockIdx.x * 4 + (threadIdx.x >> 6);
    int lane = threadIdx.x & 63;
    if (row >= nrows) return;
    const float* xr = X + (size_t)row * Ec;
    float2 v[3];
    float s = 0.f;
#pragma unroll
    for (int i = 0; i < 3; ++i) {
        v[i] = *reinterpret_cast<const float2*>(&xr[2 * lane + 128 * i]);
        s += v[i].x + v[i].y;
    }
#pragma unroll
    for (int off = 32; off >= 1; off >>= 1) s += __shfl_xor(s, off, 64);
    float mean = s * (1.0f / Ec);
    float s2 = 0.f;
#pragma unroll
    for (int i = 0; i < 3; ++i) {
        float dx = v[i].x - mean, dy = v[i].y - mean;
        s2 += dx * dx + dy * dy;
    }
#pragma unroll
    for (int off = 32; off >= 1; off >>= 1) s2 += __shfl_xor(s2, off, 64);
    float rstd = rsqrtf(s2 * (1.0f / Ec) + 1e-5f);
    u16* yr = Y + (size_t)row * Ec;
#pragma unroll
    for (int i = 0; i < 3; ++i) {
        int e = 2 * lane + 128 * i;
        float2 gv = *reinterpret_cast<const float2*>(&g[e]);
        float2 bv = *reinterpret_cast<const float2*>(&b[e]);
        ushort2 ov;
        ov.x = f2b((v[i].x - mean) * rstd * gv.x + bv.x);
        ov.y = f2b((v[i].y - mean) * rstd * gv.y + bv.y);
        *reinterpret_cast<ushort2*>(&yr[e]) = ov;
    }
}

// --- MFMA GEMM: C[*, ldC] = A[M,K](bf16) @ Wt[N,K]^T(bf16) [+bias][+R] ------
// 128x128 tile, 4 waves (2x2 of 64x64).
// PIPE3=false: r13 loop (BK=64, single 32KB buffer, 2 drains/tile).
// PIPE3=true : BK=32, TRIPLE buffer (48KB), counted vmcnt(4), depth-2
//   prefetch, ONE barrier/tile: per-wave vmcnt(4) + barrier proves tile t
//   visible AND buf (t+2)%3 free -> stage3(t+2) issues BEFORE compute3(t).
//   setprio(1) around compute cluster. Involution: 16B slot
//   p = s ^ ((row>>1)&3); source pre-swizzle (l&3)^((l>>3)&3); read
//   csw = quad ^ ((r16>>1)&3). K%32==0, K/32>=3.
// SWAP = VECEPI: operand-swapped mfma -> acc[mi][ni] = 4 consecutive n
//   (base n0+wn+ni*16+quad*4) of row m0+wm+mi*16+r16 (r18-verified layout).
// Epilogues (NV % 128 == 0 required for VECEPI):
//   VECEPI && OUTBF16 : f32x4 bias -> 16x ushort4 swizzled LDS writes ->
//                       8x b128 coalesced global stores.
//   VECEPI && !OUTBF16: direct f32x4 bias/R/store, no LDS.
//   !VECEPI           : scalar epilogue with NV guard (head GEMM).
template <bool RELU, bool RESID, bool OUTBF16, bool VECEPI, bool PIPE3>
__global__ __launch_bounds__(256) void mfma_gemm(
    const u16* __restrict__ A, const u16* __restrict__ Wt,
    const float* __restrict__ bias, const float* R, void* C,
    int K, int ldC, int NV) {
    constexpr bool SWAP = VECEPI;
    __shared__ __align__(16) u16 smem[PIPE3 ? 24576 : 16384];
    int tid = threadIdx.x;

    // bijective XCD swizzle (m204): contiguous bid chunk per XCD
    int nwg = gridDim.x * gridDim.y;
    int bid = blockIdx.y * gridDim.x + blockIdx.x;
    int q = nwg >> 3, r = nwg & 7;
    int xcd = bid & 7, idx = bid >> 3;
    int swz = (xcd < r ? xcd * (q + 1) : r * (q + 1) + (xcd - r) * q) + idx;
    int bx = swz % gridDim.x, by = swz / gridDim.x;
    int m0 = by * 128, n0 = bx * 128;

    int w = tid >> 6, lane = tid & 63;
    int wm = (w >> 1) * 64, wn = (w & 1) * 64;
    int r16 = lane & 15, quad = lane >> 4;

    f32x4 acc[4][4] = {};

    if constexpr (PIPE3) {
        u16(*As3)[128][32] = (u16(*)[128][32])smem;
        u16(*Bs3)[128][32] = (u16(*)[128][32])(smem + 3 * 128 * 32);
        // wave w stages chunks {2w, 2w+1}; chunk c = rows 16c..16c+15.
        // lane l -> row 16c + (l>>2), physical slot l&3,
        // source col slot = (l&3) ^ ((l>>3)&3).
        int rA = 2 * w * 16 + (lane >> 2);
        int colsw = ((lane & 3) ^ ((lane >> 3) & 3)) * 8;
        const u16* a0 = A + (size_t)(m0 + rA) * K + colsw;
        const u16* a1 = A + (size_t)(m0 + rA + 16) * K + colsw;
        const u16* b0 = Wt + (size_t)(n0 + rA) * K + colsw;
        const u16* b1 = Wt + (size_t)(n0 + rA + 16) * K + colsw;

        auto stage3 = [&](int buf, int t) {
            int k0 = t * 32;
            gload_lds16(a0 + k0, &As3[buf][2 * w * 16][0]);
            gload_lds16(a1 + k0, &As3[buf][2 * w * 16 + 16][0]);
            gload_lds16(b0 + k0, &Bs3[buf][2 * w * 16][0]);
            gload_lds16(b1 + k0, &Bs3[buf][2 * w * 16 + 16][0]);
        };
        int csw = (quad ^ ((r16 >> 1) & 3)) * 8;
        auto compute3 = [&](int buf) {
            bf16x8 af[4], bf[4];
#pragma unroll
            for (int i = 0; i < 4; ++i) {
                af[i] = *reinterpret_cast<const bf16x8*>(
                    &As3[buf][wm + i * 16 + r16][csw]);
                bf[i] = *reinterpret_cast<const bf16x8*>(
                    &Bs3[buf][wn + i * 16 + r16][csw]);
            }
#pragma unroll
            for (int mi = 0; mi < 4; ++mi)
#pragma unroll
                for (int ni = 0; ni < 4; ++ni) {
                    if (SWAP)
                        acc[mi][ni] = __builtin_amdgcn_mfma_f32_16x16x32_bf16(
                            bf[ni], af[mi], acc[mi][ni], 0, 0, 0);
                    else
                        acc[mi][ni] = __builtin_amdgcn_mfma_f32_16x16x32_bf16(
                            af[mi], bf[ni], acc[mi][ni], 0, 0, 0);
                }
        };

        int nt = K >> 5;  // >= 3 required
        stage3(0, 0);
        stage3(1, 1);
        int buf = 0;
        for (int t = 0; t < nt - 1; ++t) {
            // per-wave: tile-t loads landed (oldest 4 of 8 outstanding)
            asm volatile("s_waitcnt vmcnt(4)" ::: "memory");
            // all waves: tile t visible; buf (t+2)%3 done being read
            __builtin_amdgcn_s_barrier();
            __builtin_amdgcn_sched_barrier(0);
            if (t + 2 < nt) {  // issue next-next tile BEFORE compute
                int b2 = buf + 2;
                if (b2 >= 3) b2 -= 3;
                stage3(b2, t + 2);
            }
            __builtin_amdgcn_s_setprio(1);
            compute3(buf);
            __builtin_amdgcn_s_setprio(0);
            buf = (buf == 2) ? 0 : buf + 1;
        }
        asm volatile("s_waitcnt vmcnt(0)" ::: "memory");  // last tile landed
        __builtin_amdgcn_s_barrier();
        __builtin_amdgcn_sched_barrier(0);
        compute3(buf);
    } else {
        u16(*As)[64] = (u16(*)[64])smem;
        u16(*Bs)[64] = (u16(*)[64])(smem + 128 * 64);
        // staging geometry: wave w owns 1KB chunks {4w..4w+3} of each tile.
        // chunk c covers rows c*8..c*8+7; lane l -> row c*8 + (l>>3),
        // physical 8-elem slot (l&7); source col chunk = (l&7) ^ (l>>3).
        int lrow = lane >> 3;
        int scol = ((lane & 7) ^ lrow) * 8;
        const u16* ap[4];
        const u16* bp[4];
#pragma unroll
        for (int j = 0; j < 4; ++j) {
            int row = (w * 4 + j) * 8 + lrow;
            ap[j] = A + (size_t)(m0 + row) * K + scol;
            bp[j] = Wt + (size_t)(n0 + row) * K + scol;
        }
        for (int k0 = 0; k0 < K; k0 += 64) {
            __syncthreads();
#pragma unroll
            for (int j = 0; j < 4; ++j) {
                gload_lds16(ap[j], &As[(w * 4 + j) * 8][0]);
                gload_lds16(bp[j], &Bs[(w * 4 + j) * 8][0]);
                ap[j] += 64;
                bp[j] += 64;
            }
            __syncthreads();
#pragma unroll
            for (int kk = 0; kk < 2; ++kk) {
                int csw = ((kk * 4 + quad) ^ (r16 & 7)) * 8;  // swizzled col
                bf16x8 af[4], bf[4];
#pragma unroll
                for (int i = 0; i < 4; ++i) {
                    af[i] = *reinterpret_cast<const bf16x8*>(
                        &As[wm + i * 16 + r16][csw]);
                    bf[i] = *reinterpret_cast<const bf16x8*>(
                        &Bs[wn + i * 16 + r16][csw]);
                }
#pragma unroll
                for (int mi = 0; mi < 4; ++mi)
#pragma unroll
                    for (int ni = 0; ni < 4; ++ni) {
                        if (SWAP)
                            acc[mi][ni] = __builtin_amdgcn_mfma_f32_16x16x32_bf16(
                                bf[ni], af[mi], acc[mi][ni], 0, 0, 0);
                        else
                            acc[mi][ni] = __builtin_amdgcn_mfma_f32_16x16x32_bf16(
                                af[mi], bf[ni], acc[mi][ni], 0, 0, 0);
                    }
            }
        }
    }

    // ---- epilogue ----------------------------------------------------------
    if (VECEPI && OUTBF16) {
        // swapped layout: acc[mi][ni] = 4 consecutive n (gn..gn+3) of row
        // m0+wm+mi*16+r16, gn = n0+wn+ni*16+quad*4.
        f32x4 bv4[4];
#pragma unroll
        for (int ni = 0; ni < 4; ++ni) {
            int gn = n0 + wn + ni * 16 + quad * 4;
            if (bias)
                bv4[ni] = *reinterpret_cast<const f32x4*>(&bias[gn]);
            else
                bv4[ni] = f32x4{0.f, 0.f, 0.f, 0.f};
        }
        __syncthreads();  // main-loop LDS reads done
        // write: [128][128] u16, 8-elem chunk swizzled pc = cc ^ (row&15);
        // one ushort4 (8B) write per (mi,ni) at half (quad&1) of chunk.
#pragma unroll
        for (int mi = 0; mi < 4; ++mi) {
            int row = wm + mi * 16 + r16;
#pragma unroll
            for (int ni = 0; ni < 4; ++ni) {
                int colb = wn + ni * 16 + quad * 4;
                f32x4 v = acc[mi][ni] + bv4[ni];
                if (RELU) {
#pragma unroll
                    for (int e = 0; e < 4; ++e) v[e] = fmaxf(v[e], 0.f);
                }
                ushort4 ov;
                ov.x = f2b(v[0]);
                ov.y = f2b(v[1]);
                ov.z = f2b(v[2]);
                ov.w = f2b(v[3]);
                int pc = (colb >> 3) ^ (row & 15);
                *reinterpret_cast<ushort4*>(
                    &smem[row * 128 + pc * 8 + (colb & 7)]) = ov;
            }
        }
        __syncthreads();
        // read + store: thread t -> rows (t>>3)+32i, chunk (t&7)+8h
        u16* cp = (u16*)C;
#pragma unroll
        for (int i = 0; i < 4; ++i) {
            int row = (tid >> 3) + 32 * i;
#pragma unroll
            for (int h = 0; h < 2; ++h) {
                int lc = (tid & 7) + 8 * h;
                int pc = lc ^ (row & 15);
                bf16x8 val = *reinterpret_cast<const bf16x8*>(
                    &smem[row * 128 + pc * 8]);
                *reinterpret_cast<bf16x8*>(
                    &cp[(size_t)(m0 + row) * ldC + n0 + lc * 8]) = val;
            }
        }
    } else if (VECEPI) {
        // operand-swapped fp32 path: direct f32x4 bias/R/store.
        float* cp = (float*)C;
        f32x4 bv4[4];
#pragma unroll
        for (int ni = 0; ni < 4; ++ni) {
            int gn = n0 + wn + ni * 16 + quad * 4;
            if (bias)
                bv4[ni] = *reinterpret_cast<const f32x4*>(&bias[gn]);
            else
                bv4[ni] = f32x4{0.f, 0.f, 0.f, 0.f};
        }
#pragma unroll
        for (int mi = 0; mi < 4; ++mi) {
            int gm = m0 + wm + mi * 16 + r16;
#pragma unroll
            for (int ni = 0; ni < 4; ++ni) {
                int gn = n0 + wn + ni * 16 + quad * 4;
                size_t goff = (size_t)gm * ldC + gn;
                f32x4 v = acc[mi][ni] + bv4[ni];
                if (RELU) {
#pragma unroll
                    for (int e = 0; e < 4; ++e) v[e] = fmaxf(v[e], 0.f);
                }
                if (RESID) v += *reinterpret_cast<const f32x4*>(&R[goff]);
                *reinterpret_cast<f32x4*>(&cp[goff]) = v;
            }
        }
    } else {
        // scalar epilogue with NV guard (head GEMM; unswapped layout)
#pragma unroll
        for (int mi = 0; mi < 4; ++mi)
#pragma unroll
            for (int ni = 0; ni < 4; ++ni) {
                int gn = n0 + wn + ni * 16 + r16;
                if (gn >= NV) continue;
                float bvs = bias ? bias[gn] : 0.f;
#pragma unroll
                for (int reg = 0; reg < 4; ++reg) {
                    int gm = m0 + wm + mi * 16 + quad * 4 + reg;
                    float v = acc[mi][ni][reg] + bvs;
                    if (RESID) v += R[(size_t)gm * ldC + gn];
                    if (RELU) v = fmaxf(v, 0.f);
                    if (OUTBF16)
                        ((u16*)C)[(size_t)gm * ldC + gn] = f2b(v);
                    else
                        ((float*)C)[(size_t)gm * ldC + gn] = v;
                }
            }
    }
}

// --- MFMA flash attention: T14 reg-prefetch + Vt XOR-swizzle ----------------
// r30: 3rd barrier removed — Ps is wave-private (indexed by w everywhere);
// within-wave cross-lane LDS ordering is lgkmcnt-covered, no s_barrier needed.
__global__ __launch_bounds__(256) void attn_kernel(
    const u16* __restrict__ qkv, u16* __restrict__ o) {
    __shared__ u16 Qs[64][72];
    __shared__ u16 Ks[64][72];
    __shared__ u16 Vt[64][72];
    __shared__ u16 Ps[4][16][72];
    int tid = threadIdx.x;
    int tt = blockIdx.x, h = blockIdx.y, b = blockIdx.z;
    int w = tid >> 6, lane = tid & 63;
    int r16 = lane & 15, quad = lane >> 4;
    int t0 = tt * 64;
    const u16* base = qkv + (size_t)b * Tc * 1152 + h * 192;

    int sr = tid >> 2, sd = (tid & 3) * 16;
    {
        const u16* src = base + (size_t)(t0 + sr) * 1152 + sd;
        *reinterpret_cast<uint4*>(&Qs[sr][sd]) =
            *reinterpret_cast<const uint4*>(src);
        *reinterpret_cast<uint4*>(&Qs[sr][sd + 8]) =
            *reinterpret_cast<const uint4*>(src + 8);
    }
    __syncthreads();
    // hoisted Q fragments (loop-invariant; compiler can't hoist across barriers)
    bf16x8 aq0 = *reinterpret_cast<const bf16x8*>(&Qs[w * 16 + r16][quad * 8]);
    bf16x8 aq1 = *reinterpret_cast<const bf16x8*>(&Qs[w * 16 + r16][32 + quad * 8]);

    // prefetch tile 0 K/V into registers
    uint4 kr0, kr1, vr0, vr1;
    {
        const u16* ks = base + (size_t)sr * 1152 + 64 + sd;
        kr0 = *reinterpret_cast<const uint4*>(ks);
        kr1 = *reinterpret_cast<const uint4*>(ks + 8);
        const u16* vs = base + (size_t)sr * 1152 + 128 + sd;
        vr0 = *reinterpret_cast<const uint4*>(vs);
        vr1 = *reinterpret_cast<const uint4*>(vs + 8);
    }
    int vslot = sr & 7, vchk = sr >> 3;  // for swizzled Vt store

    float m_run[4], l_run[4];
#pragma unroll
    for (int r = 0; r < 4; ++r) { m_run[r] = -3.0e38f; l_run[r] = 0.f; }
    f32x4 acc_o[4] = {};

    for (int st = 0; st <= tt; ++st) {
        __syncthreads();  // prev reads of Ks/Vt done
        {
            *reinterpret_cast<uint4*>(&Ks[sr][sd]) = kr0;
            *reinterpret_cast<uint4*>(&Ks[sr][sd + 8]) = kr1;
            u16 tv[16];
            *reinterpret_cast<uint4*>(tv) = vr0;
            *reinterpret_cast<uint4*>(tv + 8) = vr1;
#pragma unroll
            for (int j = 0; j < 16; ++j) {
                int row = sd + j;
                int pc = vchk ^ ((row >> 3) & 7);
                Vt[row][pc * 8 + vslot] = tv[j];
            }
        }
        __syncthreads();  // staged tile visible
        if (st < tt) {  // issue next-tile loads; land during compute below
            const u16* ks = base + (size_t)((st + 1) * 64 + sr) * 1152 + 64 + sd;
            kr0 = *reinterpret_cast<const uint4*>(ks);
            kr1 = *reinterpret_cast<const uint4*>(ks + 8);
            const u16* vs = base + (size_t)((st + 1) * 64 + sr) * 1152 + 128 + sd;
            vr0 = *reinterpret_cast<const uint4*>(vs);
            vr1 = *reinterpret_cast<const uint4*>(vs + 8);
        }

        f32x4 acc_s[4] = {};
#pragma unroll
        for (int ni = 0; ni < 4; ++ni) {
            bf16x8 bk0 = *reinterpret_cast<const bf16x8*>(&Ks[ni * 16 + r16][quad * 8]);
            bf16x8 bk1 = *reinterpret_cast<const bf16x8*>(&Ks[ni * 16 + r16][32 + quad * 8]);
            acc_s[ni] = __builtin_amdgcn_mfma_f32_16x16x32_bf16(aq0, bk0, acc_s[ni], 0, 0, 0);
            acc_s[ni] = __builtin_amdgcn_mfma_f32_16x16x32_bf16(aq1, bk1, acc_s[ni], 0, 0, 0);
        }

        float sc[4][4];
        float mt[4] = {-3.0e38f, -3.0e38f, -3.0e38f, -3.0e38f};
#pragma unroll
        for (int ni = 0; ni < 4; ++ni)
#pragma unroll
            for (int reg = 0; reg < 4; ++reg) {
                int col = st * 64 + ni * 16 + r16;
                int row = t0 + w * 16 + quad * 4 + reg;
                float v = (col <= row) ? acc_s[ni][reg] * 0.125f : -3.0e38f;
                sc[ni][reg] = v;
                mt[reg] = fmaxf(mt[reg], v);
            }
#pragma unroll
        for (int reg = 0; reg < 4; ++reg) {
#pragma unroll
            for (int off = 1; off <= 8; off <<= 1)
                mt[reg] = fmaxf(mt[reg], __shfl_xor(mt[reg], off, 64));
        }
        float alpha[4], lt[4];
#pragma unroll
        for (int reg = 0; reg < 4; ++reg) {
            float m_new = fmaxf(m_run[reg], mt[reg]);
            alpha[reg] = __expf(m_run[reg] - m_new);
            m_run[reg] = m_new;
            lt[reg] = 0.f;
        }
#pragma unroll
        for (int ni = 0; ni < 4; ++ni)
#pragma unroll
            for (int reg = 0; reg < 4; ++reg) {
                float p = __expf(sc[ni][reg] - m_run[reg]);
                lt[reg] += p;
                Ps[w][quad * 4 + reg][ni * 16 + r16] = f2b(p);
            }
#pragma unroll
        for (int reg = 0; reg < 4; ++reg) {
#pragma unroll
            for (int off = 1; off <= 8; off <<= 1)
                lt[reg] += __shfl_xor(lt[reg], off, 64);
            l_run[reg] = l_run[reg] * alpha[reg] + lt[reg];
        }
#pragma unroll
        for (int ni = 0; ni < 4; ++ni)
#pragma unroll
            for (int reg = 0; reg < 4; ++reg) acc_o[ni][reg] *= alpha[reg];
        // NO barrier here (r30): Ps[w] is wave-private; Vt covered above.

        bf16x8 ap0 = *reinterpret_cast<const bf16x8*>(&Ps[w][r16][quad * 8]);
        bf16x8 ap1 = *reinterpret_cast<const bf16x8*>(&Ps[w][r16][32 + quad * 8]);
#pragma unroll
        for (int ni = 0; ni < 4; ++ni) {
            int vrow = ni * 16 + r16;
            int vx = (vrow >> 3) & 7;
            bf16x8 bv0 = *reinterpret_cast<const bf16x8*>(
                &Vt[vrow][(quad ^ vx) * 8]);
            bf16x8 bv1 = *reinterpret_cast<const bf16x8*>(
                &Vt[vrow][((quad + 4) ^ vx) * 8]);
            acc_o[ni] = __builtin_amdgcn_mfma_f32_16x16x32_bf16(ap0, bv0, acc_o[ni], 0, 0, 0);
            acc_o[ni] = __builtin_amdgcn_mfma_f32_16x16x32_bf16(ap1, bv1, acc_o[ni], 0, 0, 0);
        }
    }

    float inv[4];
#pragma unroll
    for (int reg = 0; reg < 4; ++reg) inv[reg] = 1.0f / l_run[reg];
#pragma unroll
    for (int ni = 0; ni < 4; ++ni)
#pragma unroll
        for (int reg = 0; reg < 4; ++reg) {
            int t = t0 + w * 16 + quad * 4 + reg;
            o[((size_t)b * Tc + t) * Ec + h * 64 + ni * 16 + r16] =
                f2b(acc_o[ni][reg] * inv[reg]);
        }
}

#define GRD(n) dim3(((n) + 255) / 256)

extern "C" void kernel_launch(void* const* d_in, const int* in_sizes, int n_in,
                              void* d_out, int out_size, void* d_ws, size_t ws_size,
                              hipStream_t stream) {
    const int* ctx = (const int*)d_in[0];
    const float* tok = (const float*)d_in[1];
    const float* pos = (const float*)d_in[2];
    const float* ln1g = (const float*)d_in[3];
    const float* ln1b = (const float*)d_in[4];
    const float* wqkv = (const float*)d_in[5];
    const float* wproj = (const float*)d_in[6];
    const float* bproj = (const float*)d_in[7];
    const float* ln2g = (const float*)d_in[8];
    const float* ln2b = (const float*)d_in[9];
    const float* w1 = (const float*)d_in[10];
    const float* b1 = (const float*)d_in[11];
    const float* w2 = (const float*)d_in[12];
    const float* b2 = (const float*)d_in[13];
    const float* lnfg = (const float*)d_in[14];
    const float* lnfb = (const float*)d_in[15];
    const float* whead = (const float*)d_in[16];
    const float* bhead = (const float*)d_in[17];
    float* out = (float*)d_out;

    // ---- workspace layout --------------------------------------------------
    char* ws = (char*)d_ws;
    float* x = (float*)ws;
    size_t off = (size_t)Mc * Ec * 4;                      // 50.3 MB
    u16* wqkvT = (u16*)(ws + off); off += (size_t)Lc * 1152 * 384 * 2;
    u16* wprojT = (u16*)(ws + off); off += (size_t)Lc * 384 * 384 * 2;
    u16* w1T = (u16*)(ws + off); off += (size_t)Lc * 1536 * 384 * 2;
    u16* w2T = (u16*)(ws + off); off += (size_t)Lc * 384 * 1536 * 2;
    u16* wheadT = (u16*)(ws + off); off += (size_t)128 * 384 * 2;  // padded
    const size_t per_b = (size_t)Tc * (Ec + 1152 + Ec + FFc) * 2;  // 1.77 MB
    if (ws_size < off + per_b) {
        poison_kernel<<<GRD(out_size), 256, 0, stream>>>(out, out_size, 200.0f);
        return;
    }
    int CB = (int)((ws_size - off) / per_b);
    if (CB > Bc) CB = Bc;
    u16* xn_c = (u16*)(ws + off);
    u16* qkv_c = xn_c + (size_t)CB * Tc * Ec;
    u16* o_c = qkv_c + (size_t)CB * Tc * 1152;
    u16* ff_c = o_c + (size_t)CB * Tc * Ec;

    // ---- weight transposes (bf16) -----------------------------------------
    trans_qkv_kernel<<<GRD(Lc * Hc * Ec * 192), 256, 0, stream>>>(wqkv, wqkvT);
    trans_w_kernel<<<GRD(Lc * Ec * Ec), 256, 0, stream>>>(wproj, wprojT, Ec, Ec);
    trans_w_kernel<<<GRD(Lc * Ec * FFc), 256, 0, stream>>>(w1, w1T, Ec, FFc);
    trans_w_kernel<<<GRD(Lc * FFc * Ec), 256, 0, stream>>>(w2, w2T, FFc, Ec);
    hipMemsetAsync(wheadT, 0, (size_t)128 * 384 * 2, stream);
    trans_head_kernel<<<GRD(Ec * Vc), 256, 0, stream>>>(whead, wheadT);

    embed_kernel<<<GRD(Mc * 96), 256, 0, stream>>>(ctx, tok, pos, x);

    for (int l = 0; l < Lc; ++l) {
        for (int b0 = 0; b0 < Bc; b0 += CB) {
            int bcnt = (Bc - b0 < CB) ? (Bc - b0) : CB;
            int rows = bcnt * Tc;
            float* xc = x + (size_t)b0 * Tc * Ec;
            ln_kernel<<<rows / 4, 256, 0, stream>>>(
                xc, xn_c, ln1g + l * Ec, ln1b + l * Ec, rows);
            mfma_gemm<false, false, true, true, true><<<dim3(1152 / 128, rows / 128), 256, 0, stream>>>(
                xn_c, wqkvT + (size_t)l * 1152 * 384, nullptr, nullptr, qkv_c,
                384, 1152, 1152);
            attn_kernel<<<dim3(Tc / 64, Hc, bcnt), 256, 0, stream>>>(qkv_c, o_c);
            mfma_gemm<false, true, false, true, true><<<dim3(Ec / 128, rows / 128), 256, 0, stream>>>(
                o_c, wprojT + (size_t)l * 384 * 384, bproj + l * Ec, xc, xc,
                384, Ec, Ec);
            ln_kernel<<<rows / 4, 256, 0, stream>>>(
                xc, xn_c, ln2g + l * Ec, ln2b + l * Ec, rows);
            mfma_gemm<true, false, true, true, true><<<dim3(FFc / 128, rows / 128), 256, 0, stream>>>(
                xn_c, w1T + (size_t)l * 1536 * 384, b1 + l * FFc, nullptr, ff_c,
                384, FFc, FFc);
            mfma_gemm<false, true, false, true, true><<<dim3(Ec / 128, rows / 128), 256, 0, stream>>>(
                ff_c, w2T + (size_t)l * 384 * 1536, b2 + l * Ec, xc, xc,
                1536, Ec, Ec);
        }
    }
    for (int b0 = 0; b0 < Bc; b0 += CB) {
        int bcnt = (Bc - b0 < CB) ? (Bc - b0) : CB;
        int rows = bcnt * Tc;
        float* xc = x + (size_t)b0 * Tc * Ec;
        ln_kernel<<<rows / 4, 256, 0, stream>>>(xc, xn_c, lnfg, lnfb, rows);
        mfma_gemm<false, false, false, false, false><<<dim3(1, rows / 128), 256, 0, stream>>>(
            xn_c, wheadT, bhead, nullptr, out + (size_t)b0 * Tc * Vc,
            384, Vc, Vc);
    }
}